// Round 3
// 491.674 us; speedup vs baseline: 1.0636x; 1.0636x over previous
//
#include <hip/hip_runtime.h>

typedef __bf16 bf16x8 __attribute__((ext_vector_type(8)));
typedef _Float16 f16x8 __attribute__((ext_vector_type(8)));
typedef float floatx4 __attribute__((ext_vector_type(4)));

__device__ __forceinline__ unsigned short f2bf(float f) {
  unsigned int u = __float_as_uint(f);
  u += 0x7FFFu + ((u >> 16) & 1u);  // RNE
  return (unsigned short)(u >> 16);
}
__device__ __forceinline__ unsigned short f2h(float f) {
  _Float16 h = (_Float16)f;
  return __builtin_bit_cast(unsigned short, h);
}
template <bool F16>
__device__ __forceinline__ unsigned short f2x(float f) {
  return F16 ? f2h(f) : f2bf(f);
}

// async global->LDS, 16B per lane. LDS dest = wave-uniform base + lane*16.
__device__ __forceinline__ void g2l16(const void* g, void* l) {
  __builtin_amdgcn_global_load_lds(
      (const __attribute__((address_space(1))) void*)g,
      (__attribute__((address_space(3))) void*)l, 16, 0, 0);
}

// ---------------------------------------------------------------------------
// C[M,N] = A[M,K] * B[N,K]^T. 128x128x64 tile, 4 waves, 4x4 of 16x16x32 MFMA.
// SWM: XOR-swizzle mask for the LDS 16B-slot index (0 = linear baseline,
// 7 = slot s of row r holds global slot s^(r&7)). Staging pre-swizzles the
// GLOBAL source address (global_load_lds dest must stay linear, rule #21);
// reads apply the same XOR. SWM=7 kills the 16-way bank conflict of the
// 128B-row-stride ds_read_b128 pattern. Q-proj runs SWM=0, K-proj SWM=7:
// same-shape within-run A/B in the per-dispatch counters.
// MFMA operands are SWAPPED (mfma(b,a)): D-col space = A-rows (C rows),
// D-row space = B-rows (C cols). Lane (qr,lr), frag (i,j), reg r holds
//   C[m0+wr+i*16+lr][n0+wc+j*16+qr*4+r]
// -> 4 consecutive cols per lane -> vectorized ushort4/float4 epilogue stores.
// INF16: A/B are fp16 (f16 MFMA); else bf16.
// MODE 0: C = relu(acc + bias[col]) -> fp16 if OUTF16 else bf16
// MODE 1: C = exp(acc - 60) -> bf16, and lrow[z*2048+row] += rowsum (atomics)
// MODE 2: C = acc / lrow[z*2048+row] -> fp32
// AF32:   A operand is fp32 in global; converted to INF16 dtype during staging.
// ---------------------------------------------------------------------------
template <int MODE, bool AF32, bool INF16, bool OUTF16, int SWM>
__global__ __launch_bounds__(256) void gemm_bt(
    const void* __restrict__ Av, int lda, long sA,
    const unsigned short* __restrict__ B, int ldb, long sB,
    void* __restrict__ Cv, int ldc, long sC,
    int K, const float* __restrict__ bias, float* __restrict__ lrow) {
  __shared__ unsigned short As[128 * 64];
  __shared__ unsigned short Bs[128 * 64];
  const int tid = threadIdx.x;
  const int wave = tid >> 6, lane = tid & 63;
  const int z = blockIdx.z;
  const unsigned short* A16 = (const unsigned short*)Av + (size_t)z * sA;
  const float* A32 = (const float*)Av + (size_t)z * sA;
  B += (size_t)z * sB;
  const int m0 = blockIdx.y * 128, n0 = blockIdx.x * 128;
  const int wr = (wave >> 1) * 64;
  const int wc = (wave & 1) * 64;
  const int qr = lane >> 4, lr = lane & 15;
  floatx4 acc[4][4] = {};

  for (int k0 = 0; k0 < K; k0 += 64) {
    __syncthreads();  // previous tile fully consumed
    if (AF32) {
#pragma unroll
      for (int it = 0; it < 8; ++it) {
        const int idx = it * 256 + tid;  // 0..2047 float4-chunks
        const int row = idx >> 4, c4 = idx & 15;
        float4 v = *(const float4*)(A32 + (size_t)(m0 + row) * lda + k0 + c4 * 4);
        // 16B slot = c4>>1, half = c4&1; write to swizzled slot (s^(row&SWM))
        const int soff = (((c4 >> 1) ^ (row & SWM)) * 2 + (c4 & 1)) * 4;
        *(ushort4*)&As[row * 64 + soff] =
            make_ushort4(f2x<INF16>(v.x), f2x<INF16>(v.y),
                         f2x<INF16>(v.z), f2x<INF16>(v.w));
      }
    } else {
#pragma unroll
      for (int it = 0; it < 4; ++it) {
        const int base = it * 256 + wave * 64;  // wave-uniform
        const int idx = base + lane;            // flat 16B-chunk index
        const int row = idx >> 3;
        const int gs = (idx & 7) ^ (row & SWM);  // inverse-swizzled global slot
        g2l16(A16 + (size_t)(m0 + row) * lda + k0 + gs * 8, &As[base * 8]);
      }
    }
#pragma unroll
    for (int it = 0; it < 4; ++it) {
      const int base = it * 256 + wave * 64;
      const int idx = base + lane;
      const int row = idx >> 3;
      const int gs = (idx & 7) ^ (row & SWM);
      g2l16(B + (size_t)(n0 + row) * ldb + k0 + gs * 8, &Bs[base * 8]);
    }
    __syncthreads();
#pragma unroll
    for (int kk = 0; kk < 64; kk += 32) {
      const int t = (kk >> 3) + qr;  // wanted global 16B slot (0..7)
      if (INF16) {
        f16x8 af[4], bf[4];
#pragma unroll
        for (int i = 0; i < 4; ++i) {
          const int ra = wr + i * 16 + lr;
          af[i] = *(const f16x8*)&As[ra * 64 + ((t ^ (ra & SWM)) * 8)];
        }
#pragma unroll
        for (int j = 0; j < 4; ++j) {
          const int rb = wc + j * 16 + lr;
          bf[j] = *(const f16x8*)&Bs[rb * 64 + ((t ^ (rb & SWM)) * 8)];
        }
#pragma unroll
        for (int i = 0; i < 4; ++i)
#pragma unroll
          for (int j = 0; j < 4; ++j)
            acc[i][j] = __builtin_amdgcn_mfma_f32_16x16x32_f16(bf[j], af[i],
                                                               acc[i][j], 0, 0, 0);
      } else {
        bf16x8 af[4], bf[4];
#pragma unroll
        for (int i = 0; i < 4; ++i) {
          const int ra = wr + i * 16 + lr;
          af[i] = *(const bf16x8*)&As[ra * 64 + ((t ^ (ra & SWM)) * 8)];
        }
#pragma unroll
        for (int j = 0; j < 4; ++j) {
          const int rb = wc + j * 16 + lr;
          bf[j] = *(const bf16x8*)&Bs[rb * 64 + ((t ^ (rb & SWM)) * 8)];
        }
#pragma unroll
        for (int i = 0; i < 4; ++i)
#pragma unroll
          for (int j = 0; j < 4; ++j)
            acc[i][j] = __builtin_amdgcn_mfma_f32_16x16x32_bf16(bf[j], af[i],
                                                                acc[i][j], 0, 0, 0);
      }
    }
  }

  // Epilogue (operand-swapped layout):
  //   row = m0 + wr + i*16 + lr ; col = n0 + wc + j*16 + qr*4 + r
  float* Cf = (float*)Cv + (size_t)z * sC;
  unsigned short* Cb = (unsigned short*)Cv + (size_t)z * sC;
#pragma unroll
  for (int i = 0; i < 4; ++i) {
    const int row = m0 + wr + i * 16 + lr;
    float rowsum = 0.0f;
    float invl = 1.0f;
    if (MODE == 2) invl = 1.0f / lrow[(size_t)z * 2048 + row];
#pragma unroll
    for (int j = 0; j < 4; ++j) {
      const int col0 = n0 + wc + j * 16 + qr * 4;
      if (MODE == 0) {
        float4 bj = *(const float4*)(bias + col0);
        float v0 = fmaxf(acc[i][j][0] + bj.x, 0.0f);
        float v1 = fmaxf(acc[i][j][1] + bj.y, 0.0f);
        float v2 = fmaxf(acc[i][j][2] + bj.z, 0.0f);
        float v3 = fmaxf(acc[i][j][3] + bj.w, 0.0f);
        *(ushort4*)&Cb[(size_t)row * ldc + col0] =
            make_ushort4(f2x<OUTF16>(v0), f2x<OUTF16>(v1),
                         f2x<OUTF16>(v2), f2x<OUTF16>(v3));
      } else if (MODE == 1) {
        float e0 = __expf(acc[i][j][0] - 60.0f);
        float e1 = __expf(acc[i][j][1] - 60.0f);
        float e2 = __expf(acc[i][j][2] - 60.0f);
        float e3 = __expf(acc[i][j][3] - 60.0f);
        *(ushort4*)&Cb[(size_t)row * ldc + col0] =
            make_ushort4(f2bf(e0), f2bf(e1), f2bf(e2), f2bf(e3));
        rowsum += (e0 + e1) + (e2 + e3);
      } else {
        *(float4*)&Cf[(size_t)row * ldc + col0] =
            make_float4(acc[i][j][0] * invl, acc[i][j][1] * invl,
                        acc[i][j][2] * invl, acc[i][j][3] * invl);
      }
    }
    if (MODE == 1) {
      // lanes lr, lr+16, lr+32, lr+48 hold the same row's partial sums
      rowsum += __shfl_xor(rowsum, 16);
      rowsum += __shfl_xor(rowsum, 32);
      if (lane < 16)
        atomicAdd(&lrow[(size_t)z * 2048 + row], rowsum);
    }
  }
}

// fp32 -> fp16/bf16 elementwise
template <bool F16>
__global__ __launch_bounds__(256) void cvt16(const float* __restrict__ in,
                                             unsigned short* __restrict__ out,
                                             int n) {
  const int i = (blockIdx.x * 256 + threadIdx.x) * 8;
  if (i >= n) return;
  float4 a = *(const float4*)(in + i);
  float4 b = *(const float4*)(in + i + 4);
  *(ushort4*)(out + i) =
      make_ushort4(f2x<F16>(a.x), f2x<F16>(a.y), f2x<F16>(a.z), f2x<F16>(a.w));
  *(ushort4*)(out + i + 4) =
      make_ushort4(f2x<F16>(b.x), f2x<F16>(b.y), f2x<F16>(b.z), f2x<F16>(b.w));
}

// W[1024][1024] fp32 -> Wt[1024][1024] fp16/bf16 transposed
template <bool F16>
__global__ __launch_bounds__(256) void wtrans(const float* __restrict__ W,
                                              unsigned short* __restrict__ Wt) {
  __shared__ unsigned short t[64][68];
  const int tid = threadIdx.x;
  const int n0 = blockIdx.x * 64, k0 = blockIdx.y * 64;
#pragma unroll
  for (int it = 0; it < 4; ++it) {
    const int idx = it * 256 + tid;
    const int kr = idx >> 4, nq = idx & 15;
    float4 v = *(const float4*)&W[(size_t)(k0 + kr) * 1024 + n0 + nq * 4];
    t[kr][nq * 4 + 0] = f2x<F16>(v.x);
    t[kr][nq * 4 + 1] = f2x<F16>(v.y);
    t[kr][nq * 4 + 2] = f2x<F16>(v.z);
    t[kr][nq * 4 + 3] = f2x<F16>(v.w);
  }
  __syncthreads();
#pragma unroll
  for (int it = 0; it < 4; ++it) {
    const int idx = it * 256 + tid;
    const int nr = idx >> 4, kq = idx & 15;
    *(ushort4*)&Wt[(size_t)(n0 + nr) * 1024 + k0 + kq * 4] =
        make_ushort4(t[kq * 4 + 0][nr], t[kq * 4 + 1][nr],
                     t[kq * 4 + 2][nr], t[kq * 4 + 3][nr]);
  }
}

// V[b][t][v] 16-bit -> Vt[b][v][t] 16-bit (dtype-agnostic)
__global__ __launch_bounds__(256) void vtrans(const unsigned short* __restrict__ V,
                                              unsigned short* __restrict__ Vt) {
  __shared__ unsigned short t[64][68];
  const int tid = threadIdx.x;
  const int v0 = blockIdx.x * 64, t0 = blockIdx.y * 64;
  const int b = blockIdx.z;
  const unsigned short* Vb = V + (size_t)b * 2048 * 1024;
  unsigned short* Vtb = Vt + (size_t)b * 1024 * 2048;
#pragma unroll
  for (int it = 0; it < 4; ++it) {
    const int idx = it * 256 + tid;
    const int tr = idx >> 4, vq = idx & 15;
    ushort4 u = *(const ushort4*)&Vb[(size_t)(t0 + tr) * 1024 + v0 + vq * 4];
    t[tr][vq * 4 + 0] = u.x;
    t[tr][vq * 4 + 1] = u.y;
    t[tr][vq * 4 + 2] = u.z;
    t[tr][vq * 4 + 3] = u.w;
  }
  __syncthreads();
#pragma unroll
  for (int it = 0; it < 4; ++it) {
    const int idx = it * 256 + tid;
    const int vr = idx >> 4, tq = idx & 15;
    *(ushort4*)&Vtb[(size_t)(v0 + vr) * 2048 + t0 + tq * 4] =
        make_ushort4(t[tq * 4 + 0][vr], t[tq * 4 + 1][vr],
                     t[tq * 4 + 2][vr], t[tq * 4 + 3][vr]);
  }
}

__global__ void zero_f32(float* __restrict__ p, int n) {
  const int i = blockIdx.x * 256 + threadIdx.x;
  if (i < n) p[i] = 0.0f;
}

// Copy half-output T[b][0..1023][1024] fp32 -> out[b][roff+0..1023][1024].
__global__ __launch_bounds__(256) void copy_half(const float* __restrict__ T,
                                                 float* __restrict__ out,
                                                 int roff) {
  const size_t i = ((size_t)blockIdx.x * 256 + threadIdx.x) * 4;
  const size_t b = i >> 20;
  const size_t rem = i & 1048575;
  float4 v = *(const float4*)(T + i);
  *(float4*)(out + b * 2097152 + (size_t)roff * 1024 + rem) = v;
}

__global__ void diag_ws(float* __restrict__ out, float mb) { out[0] = mb; }

extern "C" void kernel_launch(void* const* d_in, const int* in_sizes, int n_in,
                              void* d_out, int out_size, void* d_ws, size_t ws_size,
                              hipStream_t stream) {
  const float* X = (const float*)d_in[0];
  const float* Wq = (const float*)d_in[1];
  const float* bq = (const float*)d_in[2];
  const float* Wk = (const float*)d_in[3];
  const float* bk = (const float*)d_in[4];
  const float* Wv = (const float*)d_in[5];
  const float* bv = (const float*)d_in[6];
  float* out = (float*)d_out;
  char* ws = (char*)d_ws;
  const size_t MiB = 1ull << 20;

  // ---- BIG layout (ws >= ~134 MB): E lives in ws -> no GEMM3 aliasing ----
  const size_t B_WQT = 0, B_WKT = 2 * MiB, B_WVT = 4 * MiB;
  const size_t B_Q = 6 * MiB;     // 32 MiB fp16
  const size_t B_K = 38 * MiB;    // 32 MiB fp16
  const size_t B_E = 70 * MiB;    // 64 MiB bf16
  const size_t B_L = 134 * MiB;   // 64 KiB
  const size_t NEEDED_BIG = B_L + 65536;

  // ---- SMALL layout (proven round 4): E overlays d_out, bounce GEMM3 ----
  const size_t S_WQT = 0, S_WKT = 2 * MiB, S_WVT = 4 * MiB;
  const size_t S_Q = 6 * MiB, S_K = 38 * MiB, S_L = 70 * MiB;
  const size_t NEEDED_SMALL = S_L + 65536;

  if (ws_size >= NEEDED_BIG) {
    unsigned short* Wqt = (unsigned short*)(ws + B_WQT);
    unsigned short* Wkt = (unsigned short*)(ws + B_WKT);
    unsigned short* Wvt = (unsigned short*)(ws + B_WVT);
    unsigned short* Q   = (unsigned short*)(ws + B_Q);
    unsigned short* Kb  = (unsigned short*)(ws + B_K);
    unsigned short* E   = (unsigned short*)(ws + B_E);
    float* l            = (float*)(ws + B_L);
    // d_out: [0,32MiB) = Xh fp16 (dead after projections);
    //        [32,64MiB) = V bf16 (dead after vtrans); final: out fp32.
    unsigned short* Xh = (unsigned short*)d_out;
    unsigned short* V  = (unsigned short*)d_out + 16384ull * 1024;

    cvt16<true><<<8192, 256, 0, stream>>>(X, Xh, 16384 * 1024);
    wtrans<true><<<dim3(16, 16), 256, 0, stream>>>(Wq, Wqt);
    wtrans<true><<<dim3(16, 16), 256, 0, stream>>>(Wk, Wkt);
    wtrans<true><<<dim3(16, 16), 256, 0, stream>>>(Wv, Wvt);
    zero_f32<<<64, 256, 0, stream>>>(l, 16384);

    // projections. Q-proj: SWM=0 control; K-proj: SWM=7 treatment (A/B pair,
    // identical shape/cost). V-proj + both big GEMMs: SWM=7.
    gemm_bt<0, false, true, true, 0><<<dim3(8, 128, 1), 256, 0, stream>>>(
        Xh, 1024, 0, Wqt, 1024, 0, Q, 1024, 0, 1024, bq, nullptr);
    gemm_bt<0, false, true, true, 7><<<dim3(8, 128, 1), 256, 0, stream>>>(
        Xh, 1024, 0, Wkt, 1024, 0, Kb, 1024, 0, 1024, bk, nullptr);
    gemm_bt<0, false, true, false, 7><<<dim3(8, 128, 1), 256, 0, stream>>>(
        Xh, 1024, 0, Wvt, 1024, 0, V, 1024, 0, 1024, bv, nullptr);

    // E[b] = exp(Q K^T - 60) bf16 into ws; l rowsums
    gemm_bt<1, false, true, false, 7><<<dim3(16, 16, 8), 256, 0, stream>>>(
        Q, 1024, 2048L * 1024, Kb, 1024, 2048L * 1024,
        E, 2048, 2048L * 2048, 1024, nullptr, l);

    // V -> V^T into Q's space (Q dead after GEMM2)
    vtrans<<<dim3(16, 32, 8), 256, 0, stream>>>(V, Q);

    // out = (E * Vt^T)/l straight into d_out (no aliasing, single dispatch)
    gemm_bt<2, false, false, false, 7><<<dim3(8, 16, 8), 256, 0, stream>>>(
        E, 2048, 2048L * 2048, Q, 2048, 1024L * 2048,
        out, 1024, 2048L * 1024, 2048, nullptr, l);
    return;
  }

  if (ws_size < NEEDED_SMALL) {
    diag_ws<<<1, 1, 0, stream>>>(out, (float)(ws_size >> 20));
    return;
  }

  // ---------------- SMALL path: exact round-4 structure ----------------
  unsigned short* Wqt = (unsigned short*)(ws + S_WQT);
  unsigned short* Wkt = (unsigned short*)(ws + S_WKT);
  unsigned short* Wvt = (unsigned short*)(ws + S_WVT);
  unsigned short* Q   = (unsigned short*)(ws + S_Q);
  unsigned short* Kb  = (unsigned short*)(ws + S_K);
  float* l            = (float*)(ws + S_L);
  unsigned short* Xh = (unsigned short*)d_out;
  unsigned short* E  = (unsigned short*)d_out;

  cvt16<true><<<8192, 256, 0, stream>>>(X, Xh, 16384 * 1024);
  wtrans<true><<<dim3(16, 16), 256, 0, stream>>>(Wq, Wqt);
  wtrans<true><<<dim3(16, 16), 256, 0, stream>>>(Wk, Wkt);
  wtrans<true><<<dim3(16, 16), 256, 0, stream>>>(Wv, Wvt);
  zero_f32<<<64, 256, 0, stream>>>(l, 16384);

  gemm_bt<0, false, true, true, 0><<<dim3(8, 128, 1), 256, 0, stream>>>(
      Xh, 1024, 0, Wqt, 1024, 0, Q, 1024, 0, 1024, bq, nullptr);
  gemm_bt<0, false, true, true, 7><<<dim3(8, 128, 1), 256, 0, stream>>>(
      Xh, 1024, 0, Wkt, 1024, 0, Kb, 1024, 0, 1024, bk, nullptr);

  gemm_bt<1, false, true, false, 7><<<dim3(16, 16, 8), 256, 0, stream>>>(
      Q, 1024, 2048L * 1024, Kb, 1024, 2048L * 1024,
      E, 2048, 2048L * 2048, 1024, nullptr, l);

  gemm_bt<0, true, true, false, 7><<<dim3(8, 128, 1), 256, 0, stream>>>(
      X, 1024, 0, Wvt, 1024, 0, Kb, 1024, 0, 1024, bv, nullptr);

  vtrans<<<dim3(16, 32, 8), 256, 0, stream>>>(Kb, Q);

  float* T = (float*)Kb;
  gemm_bt<2, false, false, false, 7><<<dim3(8, 8, 8), 256, 0, stream>>>(
      E, 2048, 2048L * 2048, Q, 2048, 1024L * 2048,
      T, 1024, 1024L * 1024, 2048, nullptr, l);
  copy_half<<<8192, 256, 0, stream>>>(T, out, 0);
  gemm_bt<2, false, false, false, 7><<<dim3(8, 8, 8), 256, 0, stream>>>(
      E + 1024L * 2048, 2048, 2048L * 2048, Q, 2048, 1024L * 2048,
      T, 1024, 1024L * 1024, 2048, nullptr, l + 1024);
  copy_half<<<8192, 256, 0, stream>>>(T, out, 1024);
}

// Round 4
// 443.379 us; speedup vs baseline: 1.1795x; 1.1089x over previous
//
#include <hip/hip_runtime.h>

typedef __bf16 bf16x8 __attribute__((ext_vector_type(8)));
typedef _Float16 f16x8 __attribute__((ext_vector_type(8)));
typedef float floatx4 __attribute__((ext_vector_type(4)));

__device__ __forceinline__ unsigned short f2bf(float f) {
  unsigned int u = __float_as_uint(f);
  u += 0x7FFFu + ((u >> 16) & 1u);  // RNE
  return (unsigned short)(u >> 16);
}
__device__ __forceinline__ unsigned short f2h(float f) {
  _Float16 h = (_Float16)f;
  return __builtin_bit_cast(unsigned short, h);
}
template <bool F16>
__device__ __forceinline__ unsigned short f2x(float f) {
  return F16 ? f2h(f) : f2bf(f);
}

// async global->LDS, 16B per lane. LDS dest = wave-uniform base + lane*16.
__device__ __forceinline__ void g2l16(const void* g, void* l) {
  __builtin_amdgcn_global_load_lds(
      (const __attribute__((address_space(1))) void*)g,
      (__attribute__((address_space(3))) void*)l, 16, 0, 0);
}

// ---------------------------------------------------------------------------
// C[M,N] = A[M,K] * B[N,K]^T. 128x128x64 tile, 4 waves, 4x4 of 16x16x32 MFMA.
//
// Round-3 results: XOR swizzle killed bank conflicts (2.5e7 -> 0) but MfmaUtil
// stayed 25% -- the single-buffered 2-barrier K-loop drains vmcnt(0) every
// tile (full HBM latency exposed per K-step). This round:
//  * T4 counted-vmcnt pipeline: double-buffered LDS; stage tile t+1 BEFORE
//    computing tile t; raw s_barrier (no compiler vmcnt(0) drain) and
//    s_waitcnt vmcnt(8) so next-tile loads stay in flight across the barrier.
//  * T1 XCD chunking: flat (x,y) block id remapped (orig&7)*q + orig>>3 so
//    each XCD's L2 sees a contiguous tile range (PV was 2.8x over-fetching).
// LDS XOR swizzle (slot s of row r holds global slot s^(r&7)), pre-swizzled
// GLOBAL source + swizzled read (rule #21). MFMA operands SWAPPED (mfma(b,a)):
// lane (qr,lr), frag (i,j), reg r holds C[m0+wr+i*16+lr][n0+wc+j*16+qr*4+r]
// -> vectorized ushort4/float4 epilogue.
// MODE 0: C = relu(acc + bias[col]) -> fp16 if OUTF16 else bf16
// MODE 1: C = exp(acc - 60) -> bf16, and lrow[z*2048+row] += rowsum (atomics)
// MODE 2: C = acc / lrow[z*2048+row] -> fp32
// AF32:   A fp32 in global, converted during staging (ds_write path; keeps the
//         legacy __syncthreads() loop -- vmcnt counting doesn't apply to it).
// ---------------------------------------------------------------------------
template <int MODE, bool AF32, bool INF16, bool OUTF16>
__global__ __launch_bounds__(256) void gemm_bt(
    const void* __restrict__ Av, int lda, long sA,
    const unsigned short* __restrict__ B, int ldb, long sB,
    void* __restrict__ Cv, int ldc, long sC,
    int K, const float* __restrict__ bias, float* __restrict__ lrow) {
  __shared__ unsigned short As[2][128 * 64];
  __shared__ unsigned short Bs[2][128 * 64];
  const int tid = threadIdx.x;
  const int wave = tid >> 6, lane = tid & 63;
  const int z = blockIdx.z;
  const unsigned short* A16 = (const unsigned short*)Av + (size_t)z * sA;
  const float* A32 = (const float*)Av + (size_t)z * sA;
  B += (size_t)z * sB;

  // T1: XCD-aware bijective chunking of the (x,y) plane (nwg % 8 == 0 for all
  // our grids; guarded anyway). XCD = orig%8 processes a contiguous tile range.
  int bx = blockIdx.x, by = blockIdx.y;
  {
    const int nwg = gridDim.x * gridDim.y;
    if ((nwg & 7) == 0) {
      int flat = by * gridDim.x + bx;
      flat = (flat & 7) * (nwg >> 3) + (flat >> 3);
      bx = flat % gridDim.x;
      by = flat / gridDim.x;
    }
  }
  const int m0 = by * 128, n0 = bx * 128;
  const int wr = (wave >> 1) * 64;
  const int wc = (wave & 1) * 64;
  const int qr = lane >> 4, lr = lane & 15;
  floatx4 acc[4][4] = {};

  // stage K-tile t (non-AF32): 4+4 = 8 global_load_lds, 16B/lane.
  auto stageAB = [&](int t, int buf) {
    const int k0 = t << 6;
#pragma unroll
    for (int it = 0; it < 4; ++it) {
      const int base = it * 256 + wave * 64;  // wave-uniform LDS dest
      const int idx = base + lane;
      const int row = idx >> 3;
      const int gs = (idx & 7) ^ (row & 7);  // inverse-swizzled global slot
      g2l16(A16 + (size_t)(m0 + row) * lda + k0 + gs * 8, &As[buf][base * 8]);
    }
#pragma unroll
    for (int it = 0; it < 4; ++it) {
      const int base = it * 256 + wave * 64;
      const int idx = base + lane;
      const int row = idx >> 3;
      const int gs = (idx & 7) ^ (row & 7);
      g2l16(B + (size_t)(n0 + row) * ldb + k0 + gs * 8, &Bs[buf][base * 8]);
    }
  };

  auto computeT = [&](int buf) {
#pragma unroll
    for (int kk = 0; kk < 64; kk += 32) {
      const int slot = (kk >> 3) + qr;  // wanted global 16B slot (0..7)
      if (INF16) {
        f16x8 af[4], bf[4];
#pragma unroll
        for (int i = 0; i < 4; ++i) {
          const int ra = wr + i * 16 + lr;
          af[i] = *(const f16x8*)&As[buf][ra * 64 + ((slot ^ (ra & 7)) * 8)];
        }
#pragma unroll
        for (int j = 0; j < 4; ++j) {
          const int rb = wc + j * 16 + lr;
          bf[j] = *(const f16x8*)&Bs[buf][rb * 64 + ((slot ^ (rb & 7)) * 8)];
        }
#pragma unroll
        for (int i = 0; i < 4; ++i)
#pragma unroll
          for (int j = 0; j < 4; ++j)
            acc[i][j] = __builtin_amdgcn_mfma_f32_16x16x32_f16(
                bf[j], af[i], acc[i][j], 0, 0, 0);
      } else {
        bf16x8 af[4], bf[4];
#pragma unroll
        for (int i = 0; i < 4; ++i) {
          const int ra = wr + i * 16 + lr;
          af[i] = *(const bf16x8*)&As[buf][ra * 64 + ((slot ^ (ra & 7)) * 8)];
        }
#pragma unroll
        for (int j = 0; j < 4; ++j) {
          const int rb = wc + j * 16 + lr;
          bf[j] = *(const bf16x8*)&Bs[buf][rb * 64 + ((slot ^ (rb & 7)) * 8)];
        }
#pragma unroll
        for (int i = 0; i < 4; ++i)
#pragma unroll
          for (int j = 0; j < 4; ++j)
            acc[i][j] = __builtin_amdgcn_mfma_f32_16x16x32_bf16(
                bf[j], af[i], acc[i][j], 0, 0, 0);
      }
    }
  };

  if (!AF32) {
    // T4 pipeline: loads for tile t+1 in flight across the barrier; only
    // counted waits (vmcnt(8)) in the main loop, vmcnt(0) only at the tail.
    const int nk = K >> 6;
    stageAB(0, 0);
    for (int t = 0; t < nk; ++t) {
      const int cur = t & 1;
      if (t + 1 < nk) {
        stageAB(t + 1, cur ^ 1);
        asm volatile("s_waitcnt vmcnt(8)" ::: "memory");  // tile t landed
      } else {
        asm volatile("s_waitcnt vmcnt(0)" ::: "memory");
      }
      __builtin_amdgcn_sched_barrier(0);
      __builtin_amdgcn_s_barrier();  // all waves' tile-t loads landed
      __builtin_amdgcn_sched_barrier(0);
      computeT(cur);
      __builtin_amdgcn_sched_barrier(0);
      __builtin_amdgcn_s_barrier();  // all waves done reading buf cur
      __builtin_amdgcn_sched_barrier(0);
    }
  } else {
    // legacy synchronous loop (ds_write staging; __syncthreads drains all)
    for (int k0 = 0; k0 < K; k0 += 64) {
      __syncthreads();
#pragma unroll
      for (int it = 0; it < 8; ++it) {
        const int idx = it * 256 + tid;  // 0..2047 float4-chunks
        const int row = idx >> 4, c4 = idx & 15;
        float4 v =
            *(const float4*)(A32 + (size_t)(m0 + row) * lda + k0 + c4 * 4);
        const int soff = (((c4 >> 1) ^ (row & 7)) * 2 + (c4 & 1)) * 4;
        *(ushort4*)&As[0][row * 64 + soff] =
            make_ushort4(f2x<INF16>(v.x), f2x<INF16>(v.y), f2x<INF16>(v.z),
                         f2x<INF16>(v.w));
      }
#pragma unroll
      for (int it = 0; it < 4; ++it) {
        const int base = it * 256 + wave * 64;
        const int idx = base + lane;
        const int row = idx >> 3;
        const int gs = (idx & 7) ^ (row & 7);
        g2l16(B + (size_t)(n0 + row) * ldb + k0 + gs * 8, &Bs[0][base * 8]);
      }
      __syncthreads();
      computeT(0);
    }
  }

  // Epilogue (operand-swapped layout):
  //   row = m0 + wr + i*16 + lr ; col = n0 + wc + j*16 + qr*4 + r
  float* Cf = (float*)Cv + (size_t)z * sC;
  unsigned short* Cb = (unsigned short*)Cv + (size_t)z * sC;
#pragma unroll
  for (int i = 0; i < 4; ++i) {
    const int row = m0 + wr + i * 16 + lr;
    float rowsum = 0.0f;
    float invl = 1.0f;
    if (MODE == 2) invl = 1.0f / lrow[(size_t)z * 2048 + row];
#pragma unroll
    for (int j = 0; j < 4; ++j) {
      const int col0 = n0 + wc + j * 16 + qr * 4;
      if (MODE == 0) {
        float4 bj = *(const float4*)(bias + col0);
        float v0 = fmaxf(acc[i][j][0] + bj.x, 0.0f);
        float v1 = fmaxf(acc[i][j][1] + bj.y, 0.0f);
        float v2 = fmaxf(acc[i][j][2] + bj.z, 0.0f);
        float v3 = fmaxf(acc[i][j][3] + bj.w, 0.0f);
        *(ushort4*)&Cb[(size_t)row * ldc + col0] =
            make_ushort4(f2x<OUTF16>(v0), f2x<OUTF16>(v1), f2x<OUTF16>(v2),
                         f2x<OUTF16>(v3));
      } else if (MODE == 1) {
        float e0 = __expf(acc[i][j][0] - 60.0f);
        float e1 = __expf(acc[i][j][1] - 60.0f);
        float e2 = __expf(acc[i][j][2] - 60.0f);
        float e3 = __expf(acc[i][j][3] - 60.0f);
        *(ushort4*)&Cb[(size_t)row * ldc + col0] =
            make_ushort4(f2bf(e0), f2bf(e1), f2bf(e2), f2bf(e3));
        rowsum += (e0 + e1) + (e2 + e3);
      } else {
        *(float4*)&Cf[(size_t)row * ldc + col0] =
            make_float4(acc[i][j][0] * invl, acc[i][j][1] * invl,
                        acc[i][j][2] * invl, acc[i][j][3] * invl);
      }
    }
    if (MODE == 1) {
      // lanes lr, lr+16, lr+32, lr+48 hold the same row's partial sums
      rowsum += __shfl_xor(rowsum, 16);
      rowsum += __shfl_xor(rowsum, 32);
      if (lane < 16)
        atomicAdd(&lrow[(size_t)z * 2048 + row], rowsum);
    }
  }
}

// fp32 -> fp16/bf16 elementwise
template <bool F16>
__global__ __launch_bounds__(256) void cvt16(const float* __restrict__ in,
                                             unsigned short* __restrict__ out,
                                             int n) {
  const int i = (blockIdx.x * 256 + threadIdx.x) * 8;
  if (i >= n) return;
  float4 a = *(const float4*)(in + i);
  float4 b = *(const float4*)(in + i + 4);
  *(ushort4*)(out + i) =
      make_ushort4(f2x<F16>(a.x), f2x<F16>(a.y), f2x<F16>(a.z), f2x<F16>(a.w));
  *(ushort4*)(out + i + 4) =
      make_ushort4(f2x<F16>(b.x), f2x<F16>(b.y), f2x<F16>(b.z), f2x<F16>(b.w));
}

// W[1024][1024] fp32 -> Wt[1024][1024] fp16/bf16 transposed
template <bool F16>
__global__ __launch_bounds__(256) void wtrans(const float* __restrict__ W,
                                              unsigned short* __restrict__ Wt) {
  __shared__ unsigned short t[64][68];
  const int tid = threadIdx.x;
  const int n0 = blockIdx.x * 64, k0 = blockIdx.y * 64;
#pragma unroll
  for (int it = 0; it < 4; ++it) {
    const int idx = it * 256 + tid;
    const int kr = idx >> 4, nq = idx & 15;
    float4 v = *(const float4*)&W[(size_t)(k0 + kr) * 1024 + n0 + nq * 4];
    t[kr][nq * 4 + 0] = f2x<F16>(v.x);
    t[kr][nq * 4 + 1] = f2x<F16>(v.y);
    t[kr][nq * 4 + 2] = f2x<F16>(v.z);
    t[kr][nq * 4 + 3] = f2x<F16>(v.w);
  }
  __syncthreads();
#pragma unroll
  for (int it = 0; it < 4; ++it) {
    const int idx = it * 256 + tid;
    const int nr = idx >> 4, kq = idx & 15;
    *(ushort4*)&Wt[(size_t)(n0 + nr) * 1024 + k0 + kq * 4] =
        make_ushort4(t[kq * 4 + 0][nr], t[kq * 4 + 1][nr],
                     t[kq * 4 + 2][nr], t[kq * 4 + 3][nr]);
  }
}

// V[b][t][v] 16-bit -> Vt[b][v][t] 16-bit (dtype-agnostic)
__global__ __launch_bounds__(256) void vtrans(const unsigned short* __restrict__ V,
                                              unsigned short* __restrict__ Vt) {
  __shared__ unsigned short t[64][68];
  const int tid = threadIdx.x;
  const int v0 = blockIdx.x * 64, t0 = blockIdx.y * 64;
  const int b = blockIdx.z;
  const unsigned short* Vb = V + (size_t)b * 2048 * 1024;
  unsigned short* Vtb = Vt + (size_t)b * 1024 * 2048;
#pragma unroll
  for (int it = 0; it < 4; ++it) {
    const int idx = it * 256 + tid;
    const int tr = idx >> 4, vq = idx & 15;
    ushort4 u = *(const ushort4*)&Vb[(size_t)(t0 + tr) * 1024 + v0 + vq * 4];
    t[tr][vq * 4 + 0] = u.x;
    t[tr][vq * 4 + 1] = u.y;
    t[tr][vq * 4 + 2] = u.z;
    t[tr][vq * 4 + 3] = u.w;
  }
  __syncthreads();
#pragma unroll
  for (int it = 0; it < 4; ++it) {
    const int idx = it * 256 + tid;
    const int vr = idx >> 4, tq = idx & 15;
    *(ushort4*)&Vtb[(size_t)(v0 + vr) * 2048 + t0 + tq * 4] =
        make_ushort4(t[tq * 4 + 0][vr], t[tq * 4 + 1][vr],
                     t[tq * 4 + 2][vr], t[tq * 4 + 3][vr]);
  }
}

__global__ void zero_f32(float* __restrict__ p, int n) {
  const int i = blockIdx.x * 256 + threadIdx.x;
  if (i < n) p[i] = 0.0f;
}

// Copy half-output T[b][0..1023][1024] fp32 -> out[b][roff+0..1023][1024].
__global__ __launch_bounds__(256) void copy_half(const float* __restrict__ T,
                                                 float* __restrict__ out,
                                                 int roff) {
  const size_t i = ((size_t)blockIdx.x * 256 + threadIdx.x) * 4;
  const size_t b = i >> 20;
  const size_t rem = i & 1048575;
  float4 v = *(const float4*)(T + i);
  *(float4*)(out + b * 2097152 + (size_t)roff * 1024 + rem) = v;
}

__global__ void diag_ws(float* __restrict__ out, float mb) { out[0] = mb; }

extern "C" void kernel_launch(void* const* d_in, const int* in_sizes, int n_in,
                              void* d_out, int out_size, void* d_ws, size_t ws_size,
                              hipStream_t stream) {
  const float* X = (const float*)d_in[0];
  const float* Wq = (const float*)d_in[1];
  const float* bq = (const float*)d_in[2];
  const float* Wk = (const float*)d_in[3];
  const float* bk = (const float*)d_in[4];
  const float* Wv = (const float*)d_in[5];
  const float* bv = (const float*)d_in[6];
  float* out = (float*)d_out;
  char* ws = (char*)d_ws;
  const size_t MiB = 1ull << 20;

  // ---- BIG layout (ws >= ~134 MB): E lives in ws -> no GEMM3 aliasing ----
  const size_t B_WQT = 0, B_WKT = 2 * MiB, B_WVT = 4 * MiB;
  const size_t B_Q = 6 * MiB;     // 32 MiB fp16
  const size_t B_K = 38 * MiB;    // 32 MiB fp16
  const size_t B_E = 70 * MiB;    // 64 MiB bf16
  const size_t B_L = 134 * MiB;   // 64 KiB
  const size_t NEEDED_BIG = B_L + 65536;

  // ---- SMALL layout (proven round 4): E overlays d_out, bounce GEMM3 ----
  const size_t S_WQT = 0, S_WKT = 2 * MiB, S_WVT = 4 * MiB;
  const size_t S_Q = 6 * MiB, S_K = 38 * MiB, S_L = 70 * MiB;
  const size_t NEEDED_SMALL = S_L + 65536;

  if (ws_size >= NEEDED_BIG) {
    unsigned short* Wqt = (unsigned short*)(ws + B_WQT);
    unsigned short* Wkt = (unsigned short*)(ws + B_WKT);
    unsigned short* Wvt = (unsigned short*)(ws + B_WVT);
    unsigned short* Q   = (unsigned short*)(ws + B_Q);
    unsigned short* Kb  = (unsigned short*)(ws + B_K);
    unsigned short* E   = (unsigned short*)(ws + B_E);
    float* l            = (float*)(ws + B_L);
    // d_out: [0,32MiB) = Xh fp16 (dead after projections);
    //        [32,64MiB) = V bf16 (dead after vtrans); final: out fp32.
    unsigned short* Xh = (unsigned short*)d_out;
    unsigned short* V  = (unsigned short*)d_out + 16384ull * 1024;

    cvt16<true><<<8192, 256, 0, stream>>>(X, Xh, 16384 * 1024);
    wtrans<true><<<dim3(16, 16), 256, 0, stream>>>(Wq, Wqt);
    wtrans<true><<<dim3(16, 16), 256, 0, stream>>>(Wk, Wkt);
    wtrans<true><<<dim3(16, 16), 256, 0, stream>>>(Wv, Wvt);
    zero_f32<<<64, 256, 0, stream>>>(l, 16384);

    // projections (fp16 in; Q,K fp16 out; V bf16 out into d_out upper half)
    gemm_bt<0, false, true, true><<<dim3(8, 128, 1), 256, 0, stream>>>(
        Xh, 1024, 0, Wqt, 1024, 0, Q, 1024, 0, 1024, bq, nullptr);
    gemm_bt<0, false, true, true><<<dim3(8, 128, 1), 256, 0, stream>>>(
        Xh, 1024, 0, Wkt, 1024, 0, Kb, 1024, 0, 1024, bk, nullptr);
    gemm_bt<0, false, true, false><<<dim3(8, 128, 1), 256, 0, stream>>>(
        Xh, 1024, 0, Wvt, 1024, 0, V, 1024, 0, 1024, bv, nullptr);

    // E[b] = exp(Q K^T - 60) bf16 into ws; l rowsums
    gemm_bt<1, false, true, false><<<dim3(16, 16, 8), 256, 0, stream>>>(
        Q, 1024, 2048L * 1024, Kb, 1024, 2048L * 1024,
        E, 2048, 2048L * 2048, 1024, nullptr, l);

    // V -> V^T into Q's space (Q dead after GEMM2)
    vtrans<<<dim3(16, 32, 8), 256, 0, stream>>>(V, Q);

    // out = (E * Vt^T)/l straight into d_out (no aliasing, single dispatch)
    gemm_bt<2, false, false, false><<<dim3(8, 16, 8), 256, 0, stream>>>(
        E, 2048, 2048L * 2048, Q, 2048, 1024L * 2048,
        out, 1024, 2048L * 1024, 2048, nullptr, l);
    return;
  }

  if (ws_size < NEEDED_SMALL) {
    diag_ws<<<1, 1, 0, stream>>>(out, (float)(ws_size >> 20));
    return;
  }

  // ---------------- SMALL path: exact round-4 structure ----------------
  unsigned short* Wqt = (unsigned short*)(ws + S_WQT);
  unsigned short* Wkt = (unsigned short*)(ws + S_WKT);
  unsigned short* Wvt = (unsigned short*)(ws + S_WVT);
  unsigned short* Q   = (unsigned short*)(ws + S_Q);
  unsigned short* Kb  = (unsigned short*)(ws + S_K);
  float* l            = (float*)(ws + S_L);
  unsigned short* Xh = (unsigned short*)d_out;
  unsigned short* E  = (unsigned short*)d_out;

  cvt16<true><<<8192, 256, 0, stream>>>(X, Xh, 16384 * 1024);
  wtrans<true><<<dim3(16, 16), 256, 0, stream>>>(Wq, Wqt);
  wtrans<true><<<dim3(16, 16), 256, 0, stream>>>(Wk, Wkt);
  wtrans<true><<<dim3(16, 16), 256, 0, stream>>>(Wv, Wvt);
  zero_f32<<<64, 256, 0, stream>>>(l, 16384);

  gemm_bt<0, false, true, true><<<dim3(8, 128, 1), 256, 0, stream>>>(
      Xh, 1024, 0, Wqt, 1024, 0, Q, 1024, 0, 1024, bq, nullptr);
  gemm_bt<0, false, true, true><<<dim3(8, 128, 1), 256, 0, stream>>>(
      Xh, 1024, 0, Wkt, 1024, 0, Kb, 1024, 0, 1024, bk, nullptr);

  gemm_bt<1, false, true, false><<<dim3(16, 16, 8), 256, 0, stream>>>(
      Q, 1024, 2048L * 1024, Kb, 1024, 2048L * 1024,
      E, 2048, 2048L * 2048, 1024, nullptr, l);

  gemm_bt<0, true, true, false><<<dim3(8, 128, 1), 256, 0, stream>>>(
      X, 1024, 0, Wvt, 1024, 0, Kb, 1024, 0, 1024, bv, nullptr);

  vtrans<<<dim3(16, 32, 8), 256, 0, stream>>>(Kb, Q);

  float* T = (float*)Kb;
  gemm_bt<2, false, false, false><<<dim3(8, 8, 8), 256, 0, stream>>>(
      E, 2048, 2048L * 2048, Q, 2048, 1024L * 2048,
      T, 1024, 1024L * 1024, 2048, nullptr, l);
  copy_half<<<8192, 256, 0, stream>>>(T, out, 0);
  gemm_bt<2, false, false, false><<<dim3(8, 8, 8), 256, 0, stream>>>(
      E + 1024L * 2048, 2048, 2048L * 2048, Q, 2048, 1024L * 2048,
      T, 1024, 1024L * 1024, 2048, nullptr, l + 1024);
  copy_half<<<8192, 256, 0, stream>>>(T, out, 1024);
}